// Round 1
// baseline (784.940 us; speedup 1.0000x reference)
//
#include <hip/hip_runtime.h>
#include <hip/hip_bf16.h>
#include <math.h>

#define NB 2
#define C 256
#define P 4096   // 64*64
#define EPS_F 1e-5f

typedef __attribute__((ext_vector_type(8))) short short8;
typedef __attribute__((ext_vector_type(4))) float f32x4;

// ---------------- K1: per-channel mean of featureT over n,h,w ----------------
__global__ void k_mean(const float* __restrict__ fT, float* __restrict__ mean) {
    int c = blockIdx.x;
    int t = threadIdx.x;
    const float* p0 = fT + (size_t)c * P;          // n=0
    const float* p1 = fT + (size_t)(C + c) * P;    // n=1
    float s = 0.f;
    for (int i = t; i < P; i += 256) s += p0[i] + p1[i];
    __shared__ float red[256];
    red[t] = s; __syncthreads();
    for (int o = 128; o > 0; o >>= 1) { if (t < o) red[t] += red[t + o]; __syncthreads(); }
    if (t == 0) mean[c] = red[0] * (1.f / 8192.f);
}

// ---------------- K2: per-pixel 1/||x - mean|| ----------------
__global__ void k_norm(const float* __restrict__ f, const float* __restrict__ mean,
                       float* __restrict__ rnorm) {
    // grid: x = p-chunk of 64 (64 blocks), y = n (2); block 256 = 64p x 4 c-groups
    __shared__ float mn[C];
    __shared__ float part[4][64];
    int t = threadIdx.x;
    mn[t] = mean[t];
    __syncthreads();
    int n = blockIdx.y;
    int p0 = blockIdx.x * 64;
    int pl = t & 63, cg = t >> 6;
    const float* base = f + (size_t)n * C * P + p0 + pl;
    float acc = 0.f;
    #pragma unroll 4
    for (int cc = 0; cc < 64; cc++) {
        int c = cg * 64 + cc;
        float v = base[(size_t)c * P] - mn[c];
        acc += v * v;
    }
    part[cg][pl] = acc;
    __syncthreads();
    if (t < 64) {
        float s = part[0][t] + part[1][t] + part[2][t] + part[3][t];
        rnorm[n * P + p0 + t] = rsqrtf(s);
    }
}

// ---------------- K3: transpose NCHW -> [n][p][c], center+scale, cast bf16 ----------------
__global__ void k_pack(const float* __restrict__ f, const float* __restrict__ mean,
                       const float* __restrict__ rnorm, __hip_bfloat16* __restrict__ out) {
    // grid: x = p-tile (64), y = c-tile (4), z = n (2); block 256
    __shared__ float tile[64][65];
    int t = threadIdx.x;
    int n = blockIdx.z, c0 = blockIdx.y * 64, p0 = blockIdx.x * 64;
    const float* base = f + ((size_t)n * C + c0) * P + p0;
    #pragma unroll
    for (int i = 0; i < 16; i++) {
        int idx = t + 256 * i;
        int cc = idx >> 6, pp = idx & 63;
        tile[cc][pp] = base[(size_t)cc * P + pp] - mean[c0 + cc];
    }
    __syncthreads();
    #pragma unroll
    for (int i = 0; i < 16; i++) {
        int idx = t + 256 * i;
        int pp = idx >> 6, cc = idx & 63;
        float v = tile[cc][pp] * rnorm[n * P + p0 + pp];
        out[(size_t)(n * P + p0 + pp) * C + c0 + cc] = __float2bfloat16(v);
    }
}

// ---------------- K4: dist[n][q][p] = sum_c TI[n][q][c]*TT[n][p][c] (bf16 MFMA) ----------------
__global__ __launch_bounds__(256) void k_gemm(const __hip_bfloat16* __restrict__ TI,
                                              const __hip_bfloat16* __restrict__ TT,
                                              float* __restrict__ dist) {
    // grid: x = p-tile(32), y = q-tile(32), z = n(2); block 256 (4 waves, 2x2 of 64x64)
    int lane = threadIdx.x & 63, wid = threadIdx.x >> 6;
    int n = blockIdx.z;
    int qw = blockIdx.y * 128 + (wid >> 1) * 64;
    int pw = blockIdx.x * 128 + (wid & 1) * 64;
    const __hip_bfloat16* A = TI + (size_t)n * P * C;
    const __hip_bfloat16* B = TT + (size_t)n * P * C;
    f32x4 acc[4][4];
    #pragma unroll
    for (int m = 0; m < 4; m++)
        #pragma unroll
        for (int nt = 0; nt < 4; nt++)
            acc[m][nt] = (f32x4){0.f, 0.f, 0.f, 0.f};
    int kbase = (lane >> 4) * 8;
    int rA = lane & 15;
    #pragma unroll
    for (int kk = 0; kk < 8; kk++) {
        short8 a[4], b[4];
        #pragma unroll
        for (int m = 0; m < 4; m++)
            a[m] = *reinterpret_cast<const short8*>(A + (size_t)(qw + m * 16 + rA) * C + kk * 32 + kbase);
        #pragma unroll
        for (int nt = 0; nt < 4; nt++)
            b[nt] = *reinterpret_cast<const short8*>(B + (size_t)(pw + nt * 16 + rA) * C + kk * 32 + kbase);
        #pragma unroll
        for (int m = 0; m < 4; m++)
            #pragma unroll
            for (int nt = 0; nt < 4; nt++)
                acc[m][nt] = __builtin_amdgcn_mfma_f32_16x16x32_bf16(a[m], b[nt], acc[m][nt], 0, 0, 0);
    }
    int rowoff = (lane >> 4) * 4, col = lane & 15;
    float* D = dist + (size_t)n * P * P;
    #pragma unroll
    for (int m = 0; m < 4; m++)
        #pragma unroll
        for (int nt = 0; nt < 4; nt++)
            #pragma unroll
            for (int j = 0; j < 4; j++)
                D[(size_t)(qw + m * 16 + rowoff + j) * P + pw + nt * 16 + col] = acc[m][nt][j];
}

// ---------------- K5: per-row max -> t2, then Z; store t2, maxd, 1/Z ----------------
__global__ void k_rows(const float* __restrict__ dist, float* __restrict__ t2a,
                       float* __restrict__ mda, float* __restrict__ rza) {
    // grid: x = q-chunk(32), y = n(2); block 256 (4 waves, 32 rows each)
    int lane = threadIdx.x & 63, w = threadIdx.x >> 6;
    int n = blockIdx.y;
    int q0 = blockIdx.x * 128 + w * 32;
    for (int r = 0; r < 32; r++) {
        int q = q0 + r;
        const float* drow = dist + ((size_t)n * P + q) * P;
        float m = -1e30f;
        for (int i = lane; i < P; i += 64) m = fmaxf(m, drow[i]);
        #pragma unroll
        for (int o = 32; o > 0; o >>= 1) m = fmaxf(m, __shfl_xor(m, o));
        float t2 = 5.f / ((1.f - m) * 0.5f + EPS_F);
        float z = 0.f;
        for (int i = lane; i < P; i += 64) z += __expf(t2 * (drow[i] - m));
        #pragma unroll
        for (int o = 32; o > 0; o >>= 1) z += __shfl_xor(z, o);
        if (lane == 0) {
            t2a[n * P + q] = t2;
            mda[n * P + q] = m;
            rza[n * P + q] = 1.f / z;
        }
    }
}

// ---------------- K6: colmax[n][p] = max_q exp(t2*(d-maxd))/Z ----------------
__global__ void k_colmax(const float* __restrict__ dist, const float* __restrict__ t2a,
                         const float* __restrict__ mda, const float* __restrict__ rza,
                         unsigned int* __restrict__ colmax) {
    // grid: x = p-chunk(16), y = q-seg(8), z = n(2); block 256
    __shared__ float st2[512], smd[512], srz[512];
    int t = threadIdx.x;
    int n = blockIdx.z, q0 = blockIdx.y * 512, p = blockIdx.x * 256 + t;
    for (int i = t; i < 512; i += 256) {
        st2[i] = t2a[n * P + q0 + i];
        smd[i] = mda[n * P + q0 + i];
        srz[i] = rza[n * P + q0 + i];
    }
    __syncthreads();
    const float* base = dist + ((size_t)n * P + q0) * P + p;
    float local = 0.f;
    for (int j = 0; j < 512; j++) {
        float d = base[(size_t)j * P];
        float v = __expf(st2[j] * (d - smd[j])) * srz[j];
        local = fmaxf(local, v);
    }
    atomicMax(&colmax[n * P + p], __float_as_uint(local));
}

// ---------------- K7: final reduce: -log(mean_p colmax), mean over n ----------------
__global__ void k_final(const unsigned int* __restrict__ colmax, float* __restrict__ out) {
    __shared__ float red[256];
    int t = threadIdx.x;
    float cx[NB];
    for (int n = 0; n < NB; n++) {
        float s = 0.f;
        for (int i = t; i < P; i += 256) s += __uint_as_float(colmax[n * P + i]);
        red[t] = s; __syncthreads();
        for (int o = 128; o > 0; o >>= 1) { if (t < o) red[t] += red[t + o]; __syncthreads(); }
        cx[n] = -logf(red[0] * (1.f / (float)P));
        __syncthreads();
    }
    if (t == 0) out[0] = 0.5f * (cx[0] + cx[1]);
}

extern "C" void kernel_launch(void* const* d_in, const int* in_sizes, int n_in,
                              void* d_out, int out_size, void* d_ws, size_t ws_size,
                              hipStream_t stream) {
    const float* fT = (const float*)d_in[0];   // featureT
    const float* fI = (const float*)d_in[1];   // featureI
    float* out = (float*)d_out;

    char* ws = (char*)d_ws;
    // workspace layout (total ~136.2 MiB)
    float*          dist   = (float*)(ws);                               // 134217728 B
    __hip_bfloat16* TI     = (__hip_bfloat16*)(ws + 134217728);          // 4 MiB
    __hip_bfloat16* TT     = (__hip_bfloat16*)(ws + 134217728 + 4194304);// 4 MiB
    size_t off = 134217728 + 2 * 4194304;
    float* mean   = (float*)(ws + off); off += 1024;
    float* rnormI = (float*)(ws + off); off += 32768;
    float* rnormT = (float*)(ws + off); off += 32768;
    float* t2a    = (float*)(ws + off); off += 32768;
    float* mda    = (float*)(ws + off); off += 32768;
    float* rza    = (float*)(ws + off); off += 32768;
    unsigned int* colmax = (unsigned int*)(ws + off); off += 32768;

    hipMemsetAsync(colmax, 0, NB * P * sizeof(unsigned int), stream);

    k_mean<<<256, 256, 0, stream>>>(fT, mean);
    k_norm<<<dim3(64, 2), 256, 0, stream>>>(fI, mean, rnormI);
    k_norm<<<dim3(64, 2), 256, 0, stream>>>(fT, mean, rnormT);
    k_pack<<<dim3(64, 4, 2), 256, 0, stream>>>(fI, mean, rnormI, TI);
    k_pack<<<dim3(64, 4, 2), 256, 0, stream>>>(fT, mean, rnormT, TT);
    k_gemm<<<dim3(32, 32, 2), 256, 0, stream>>>(TI, TT, dist);
    k_rows<<<dim3(32, 2), 256, 0, stream>>>(dist, t2a, mda, rza);
    k_colmax<<<dim3(16, 8, 2), 256, 0, stream>>>(dist, t2a, mda, rza, colmax);
    k_final<<<1, 256, 0, stream>>>(colmax, out);
}

// Round 2
// 162.265 us; speedup vs baseline: 4.8374x; 4.8374x over previous
//
#include <hip/hip_runtime.h>
#include <hip/hip_bf16.h>
#include <math.h>

#define NB 2
#define C 256
#define P 4096   // 64*64
#define EPS_F 1e-5f

typedef __attribute__((ext_vector_type(8))) short short8;
typedef __attribute__((ext_vector_type(4))) float f32x4;

// ---------------- K1: per-channel mean of featureT over n,h,w ----------------
__global__ void k_mean(const float* __restrict__ fT, float* __restrict__ mean) {
    int c = blockIdx.x;
    int t = threadIdx.x;
    const float* p0 = fT + (size_t)c * P;          // n=0
    const float* p1 = fT + (size_t)(C + c) * P;    // n=1
    float s = 0.f;
    for (int i = t; i < P; i += 256) s += p0[i] + p1[i];
    __shared__ float red[256];
    red[t] = s; __syncthreads();
    for (int o = 128; o > 0; o >>= 1) { if (t < o) red[t] += red[t + o]; __syncthreads(); }
    if (t == 0) mean[c] = red[0] * (1.f / 8192.f);
}

// ---------------- K2: per-pixel 1/||x - mean|| ----------------
__global__ void k_norm(const float* __restrict__ f, const float* __restrict__ mean,
                       float* __restrict__ rnorm) {
    // grid: x = p-chunk of 64 (64 blocks), y = n (2); block 256 = 64p x 4 c-groups
    __shared__ float mn[C];
    __shared__ float part[4][64];
    int t = threadIdx.x;
    mn[t] = mean[t];
    __syncthreads();
    int n = blockIdx.y;
    int p0 = blockIdx.x * 64;
    int pl = t & 63, cg = t >> 6;
    const float* base = f + (size_t)n * C * P + p0 + pl;
    float acc = 0.f;
    #pragma unroll 4
    for (int cc = 0; cc < 64; cc++) {
        int c = cg * 64 + cc;
        float v = base[(size_t)c * P] - mn[c];
        acc += v * v;
    }
    part[cg][pl] = acc;
    __syncthreads();
    if (t < 64) {
        float s = part[0][t] + part[1][t] + part[2][t] + part[3][t];
        rnorm[n * P + p0 + t] = rsqrtf(s);
    }
}

// ---------------- K3: transpose NCHW -> [n][p][c], center+scale, cast bf16 ----------------
__global__ void k_pack(const float* __restrict__ f, const float* __restrict__ mean,
                       const float* __restrict__ rnorm, __hip_bfloat16* __restrict__ out) {
    // grid: x = p-tile (64), y = c-tile (4), z = n (2); block 256
    __shared__ float tile[64][65];
    int t = threadIdx.x;
    int n = blockIdx.z, c0 = blockIdx.y * 64, p0 = blockIdx.x * 64;
    const float* base = f + ((size_t)n * C + c0) * P + p0;
    #pragma unroll
    for (int i = 0; i < 16; i++) {
        int idx = t + 256 * i;
        int cc = idx >> 6, pp = idx & 63;
        tile[cc][pp] = base[(size_t)cc * P + pp] - mean[c0 + cc];
    }
    __syncthreads();
    #pragma unroll
    for (int i = 0; i < 16; i++) {
        int idx = t + 256 * i;
        int pp = idx >> 6, cc = idx & 63;
        float v = tile[cc][pp] * rnorm[n * P + p0 + pp];
        out[(size_t)(n * P + p0 + pp) * C + c0 + cc] = __float2bfloat16(v);
    }
}

// ---------------- K4: dist[n][q][p] = sum_c TI[n][q][c]*TT[n][p][c] (bf16 MFMA) ----------------
__global__ __launch_bounds__(256) void k_gemm(const __hip_bfloat16* __restrict__ TI,
                                              const __hip_bfloat16* __restrict__ TT,
                                              float* __restrict__ dist) {
    // grid: x = p-tile(32), y = q-tile(32), z = n(2); block 256 (4 waves, 2x2 of 64x64)
    int lane = threadIdx.x & 63, wid = threadIdx.x >> 6;
    int n = blockIdx.z;
    int qw = blockIdx.y * 128 + (wid >> 1) * 64;
    int pw = blockIdx.x * 128 + (wid & 1) * 64;
    const __hip_bfloat16* A = TI + (size_t)n * P * C;
    const __hip_bfloat16* B = TT + (size_t)n * P * C;
    f32x4 acc[4][4];
    #pragma unroll
    for (int m = 0; m < 4; m++)
        #pragma unroll
        for (int nt = 0; nt < 4; nt++)
            acc[m][nt] = (f32x4){0.f, 0.f, 0.f, 0.f};
    int kbase = (lane >> 4) * 8;
    int rA = lane & 15;
    #pragma unroll
    for (int kk = 0; kk < 8; kk++) {
        short8 a[4], b[4];
        #pragma unroll
        for (int m = 0; m < 4; m++)
            a[m] = *reinterpret_cast<const short8*>(A + (size_t)(qw + m * 16 + rA) * C + kk * 32 + kbase);
        #pragma unroll
        for (int nt = 0; nt < 4; nt++)
            b[nt] = *reinterpret_cast<const short8*>(B + (size_t)(pw + nt * 16 + rA) * C + kk * 32 + kbase);
        #pragma unroll
        for (int m = 0; m < 4; m++)
            #pragma unroll
            for (int nt = 0; nt < 4; nt++)
                acc[m][nt] = __builtin_amdgcn_mfma_f32_16x16x32_bf16(a[m], b[nt], acc[m][nt], 0, 0, 0);
    }
    int rowoff = (lane >> 4) * 4, col = lane & 15;
    float* D = dist + (size_t)n * P * P;
    #pragma unroll
    for (int m = 0; m < 4; m++)
        #pragma unroll
        for (int nt = 0; nt < 4; nt++)
            #pragma unroll
            for (int j = 0; j < 4; j++)
                D[(size_t)(qw + m * 16 + rowoff + j) * P + pw + nt * 16 + col] = acc[m][nt][j];
}

// ---------------- K5: per-row max -> t2 and Z; one block per row ----------------
__global__ __launch_bounds__(256) void k_rows(const float* __restrict__ dist,
                                              float* __restrict__ t2a,
                                              float* __restrict__ mda,
                                              float* __restrict__ rza) {
    // grid.x = NB*P = 8192 (one block per dist row); block 256
    int row = blockIdx.x;
    int t = threadIdx.x;
    const f32x4* src = (const f32x4*)(dist + (size_t)row * P);
    f32x4 v[4];
    #pragma unroll
    for (int i = 0; i < 4; i++) v[i] = src[t + 256 * i];
    float m = -1e30f;
    #pragma unroll
    for (int i = 0; i < 4; i++)
        m = fmaxf(m, fmaxf(fmaxf(v[i][0], v[i][1]), fmaxf(v[i][2], v[i][3])));
    #pragma unroll
    for (int o = 32; o > 0; o >>= 1) m = fmaxf(m, __shfl_xor(m, o));
    __shared__ float redm[4];
    __shared__ float redz[4];
    int lane = t & 63, w = t >> 6;
    if (lane == 0) redm[w] = m;
    __syncthreads();
    m = fmaxf(fmaxf(redm[0], redm[1]), fmaxf(redm[2], redm[3]));
    float t2 = 5.f / ((1.f - m) * 0.5f + EPS_F);
    float z = 0.f;
    #pragma unroll
    for (int i = 0; i < 4; i++)
        #pragma unroll
        for (int j = 0; j < 4; j++)
            z += __expf(t2 * (v[i][j] - m));
    #pragma unroll
    for (int o = 32; o > 0; o >>= 1) z += __shfl_xor(z, o);
    if (lane == 0) redz[w] = z;
    __syncthreads();
    if (t == 0) {
        float zz = redz[0] + redz[1] + redz[2] + redz[3];
        t2a[row] = t2; mda[row] = m; rza[row] = 1.f / zz;
    }
}

// ---------------- K6: colmax[n][p] = max_q exp(t2*(d-maxd))/Z ----------------
__global__ void k_colmax(const float* __restrict__ dist, const float* __restrict__ t2a,
                         const float* __restrict__ mda, const float* __restrict__ rza,
                         unsigned int* __restrict__ colmax) {
    // grid: x = p-chunk(16), y = q-seg(16), z = n(2); block 256
    __shared__ float st2[256], smd[256], srz[256];
    int t = threadIdx.x;
    int n = blockIdx.z, q0 = blockIdx.y * 256, p = blockIdx.x * 256 + t;
    st2[t] = t2a[n * P + q0 + t];
    smd[t] = mda[n * P + q0 + t];
    srz[t] = rza[n * P + q0 + t];
    __syncthreads();
    const float* base = dist + ((size_t)n * P + q0) * P + p;
    float local = 0.f;
    for (int j = 0; j < 256; j++) {
        float d = base[(size_t)j * P];
        float v = __expf(st2[j] * (d - smd[j])) * srz[j];
        local = fmaxf(local, v);
    }
    atomicMax(&colmax[n * P + p], __float_as_uint(local));
}

// ---------------- K7: final reduce: -log(mean_p colmax), mean over n ----------------
__global__ void k_final(const unsigned int* __restrict__ colmax, float* __restrict__ out) {
    __shared__ float red[256];
    int t = threadIdx.x;
    float cx[NB];
    for (int n = 0; n < NB; n++) {
        float s = 0.f;
        for (int i = t; i < P; i += 256) s += __uint_as_float(colmax[n * P + i]);
        red[t] = s; __syncthreads();
        for (int o = 128; o > 0; o >>= 1) { if (t < o) red[t] += red[t + o]; __syncthreads(); }
        cx[n] = -logf(red[0] * (1.f / (float)P));
        __syncthreads();
    }
    if (t == 0) out[0] = 0.5f * (cx[0] + cx[1]);
}

extern "C" void kernel_launch(void* const* d_in, const int* in_sizes, int n_in,
                              void* d_out, int out_size, void* d_ws, size_t ws_size,
                              hipStream_t stream) {
    const float* fT = (const float*)d_in[0];   // featureT
    const float* fI = (const float*)d_in[1];   // featureI
    float* out = (float*)d_out;

    char* ws = (char*)d_ws;
    // workspace layout (total ~136.2 MiB)
    float*          dist   = (float*)(ws);                               // 134217728 B
    __hip_bfloat16* TI     = (__hip_bfloat16*)(ws + 134217728);          // 4 MiB
    __hip_bfloat16* TT     = (__hip_bfloat16*)(ws + 134217728 + 4194304);// 4 MiB
    size_t off = 134217728 + 2 * 4194304;
    float* mean   = (float*)(ws + off); off += 1024;
    float* rnormI = (float*)(ws + off); off += 32768;
    float* rnormT = (float*)(ws + off); off += 32768;
    float* t2a    = (float*)(ws + off); off += 32768;
    float* mda    = (float*)(ws + off); off += 32768;
    float* rza    = (float*)(ws + off); off += 32768;
    unsigned int* colmax = (unsigned int*)(ws + off); off += 32768;

    hipMemsetAsync(colmax, 0, NB * P * sizeof(unsigned int), stream);

    k_mean<<<256, 256, 0, stream>>>(fT, mean);
    k_norm<<<dim3(64, 2), 256, 0, stream>>>(fI, mean, rnormI);
    k_norm<<<dim3(64, 2), 256, 0, stream>>>(fT, mean, rnormT);
    k_pack<<<dim3(64, 4, 2), 256, 0, stream>>>(fI, mean, rnormI, TI);
    k_pack<<<dim3(64, 4, 2), 256, 0, stream>>>(fT, mean, rnormT, TT);
    k_gemm<<<dim3(32, 32, 2), 256, 0, stream>>>(TI, TT, dist);
    k_rows<<<8192, 256, 0, stream>>>(dist, t2a, mda, rza);
    k_colmax<<<dim3(16, 16, 2), 256, 0, stream>>>(dist, t2a, mda, rza, colmax);
    k_final<<<1, 256, 0, stream>>>(colmax, out);
}